// Round 2
// baseline (1108.088 us; speedup 1.0000x reference)
//
#include <hip/hip_runtime.h>
#include <hip/hip_bf16.h>

typedef __bf16 bf16x8 __attribute__((ext_vector_type(8)));
typedef float  f32x4  __attribute__((ext_vector_type(4)));

#define EDGES_TOTAL 1000000
#define TILES (EDGES_TOTAL / 32)   // 31250 wave-tiles of 32 edges

__device__ __forceinline__ bf16x8 load_cvt8(const float* __restrict__ p) {
    f32x4 a = *(const f32x4*)p;
    f32x4 b = *(const f32x4*)(p + 4);
    bf16x8 r;
    r[0] = (__bf16)a[0]; r[1] = (__bf16)a[1]; r[2] = (__bf16)a[2]; r[3] = (__bf16)a[3];
    r[4] = (__bf16)b[0]; r[5] = (__bf16)b[1]; r[6] = (__bf16)b[2]; r[7] = (__bf16)b[3];
    return r;
}

// 512 threads/block (8 waves) sharing one 64 KiB W-copy in LDS:
// 2 blocks/CU -> 16 waves/CU (50% occupancy), VGPR=128 allows exactly 4 waves/SIMD.
__global__ __launch_bounds__(512, 4) void sampleall_fused(
    const float* __restrict__ emb, const float* __restrict__ rel,
    const float* __restrict__ tokeys, const float* __restrict__ toqueries,
    const int* __restrict__ si, const int* __restrict__ pi, const int* __restrict__ oi,
    float* __restrict__ out)
{
    // W_k, W_q as bf16 in LDS. Within each 256B row, the sixteen 16B granules
    // are XOR-swizzled by (row&7) -> conflict-free ds_read_b128 on the read side.
    __shared__ __align__(16) __bf16 ldsW[2][128 * 128];

    const int tid = threadIdx.x;
    #pragma unroll
    for (int it = 0; it < 8; ++it) {
        int gidx = tid + it * 512;        // 0..4095 : 2 mats x 128 rows x 16 chunks
        int m    = gidx >> 11;
        int rm   = gidx & 2047;
        int row  = rm >> 4;
        int ch   = rm & 15;
        const float* src = (m ? toqueries : tokeys) + row * 128 + ch * 8;
        bf16x8 b = load_cvt8(src);
        int byteoff = row * 256 + ((ch * 16) ^ ((row & 7) << 4));
        *(bf16x8*)((char*)(&ldsW[m][0]) + byteoff) = b;
    }
    __syncthreads();

    const int lane = tid & 63;
    const int wid  = tid >> 6;     // 0..7
    const int c    = lane & 15;    // edge slot within half (and W fragment row)
    const int g    = lane >> 4;    // k-group
    const int xm   = (c & 7) << 4; // LDS swizzle mask for this lane's W rows
    const char* wkbase = (const char*)(&ldsW[0][0]) + c * 256;
    const char* wqbase = (const char*)(&ldsW[1][0]) + c * 256;

    const int wtotal = (int)gridDim.x * 8;
    for (int tile = (int)blockIdx.x * 8 + wid; tile < TILES; tile += wtotal) {
        const int e0 = tile * 32;
        const int sA = si[e0 + c], sB = si[e0 + 16 + c];
        const int oA = oi[e0 + c], oB = oi[e0 + 16 + c];
        const int pA = pi[e0 + c], pB = pi[e0 + 16 + c];
        const float* ps0 = emb + (size_t)sA * 128 + g * 8;
        const float* ps1 = emb + (size_t)sB * 128 + g * 8;
        const float* po0 = emb + (size_t)oA * 128 + g * 8;
        const float* po1 = emb + (size_t)oB * 128 + g * 8;

        f32x4 accK0[8], accK1[8], accQ0[8], accQ1[8];
        #pragma unroll
        for (int t = 0; t < 8; ++t) {
            accK0[t] = (f32x4){0.f, 0.f, 0.f, 0.f};
            accK1[t] = (f32x4){0.f, 0.f, 0.f, 0.f};
            accQ0[t] = (f32x4){0.f, 0.f, 0.f, 0.f};
            accQ1[t] = (f32x4){0.f, 0.f, 0.f, 0.f};
        }

        #pragma unroll
        for (int j0 = 0; j0 < 4; ++j0) {
            // B-fragments: 8 contiguous k-elements of the gathered rows (f32 -> bf16)
            bf16x8 bs0 = load_cvt8(ps0 + j0 * 32);
            bf16x8 bs1 = load_cvt8(ps1 + j0 * 32);
            bf16x8 bo0 = load_cvt8(po0 + j0 * 32);
            bf16x8 bo1 = load_cvt8(po1 + j0 * 32);
            const int offj = ((j0 * 64 + g * 16) ^ xm);   // swizzled within-row byte offset
            #pragma unroll
            for (int t = 0; t < 8; ++t) {
                bf16x8 aK = *(const bf16x8*)(wkbase + t * 4096 + offj);
                accK0[t] = __builtin_amdgcn_mfma_f32_16x16x32_bf16(aK, bs0, accK0[t], 0, 0, 0);
                accK1[t] = __builtin_amdgcn_mfma_f32_16x16x32_bf16(aK, bs1, accK1[t], 0, 0, 0);
                bf16x8 aQ = *(const bf16x8*)(wqbase + t * 4096 + offj);
                accQ0[t] = __builtin_amdgcn_mfma_f32_16x16x32_bf16(aQ, bo0, accQ0[t], 0, 0, 0);
                accQ1[t] = __builtin_amdgcn_mfma_f32_16x16x32_bf16(aQ, bo1, accQ1[t], 0, 0, 0);
            }
        }

        // Epilogue: lane (g,c) holds semb/qemb features i = t*16 + g*4 + r of its edge.
        float d0 = 0.f, d1 = 0.f;
        const float* relA = rel + (size_t)pA * 128 + g * 4;
        const float* relB = rel + (size_t)pB * 128 + g * 4;
        #pragma unroll
        for (int t = 0; t < 8; ++t) {
            f32x4 rA = *(const f32x4*)(relA + t * 16);
            f32x4 rB = *(const f32x4*)(relB + t * 16);
            #pragma unroll
            for (int r = 0; r < 4; ++r) {
                d0 += accK0[t][r] * accQ0[t][r] * rA[r];
                d1 += accK1[t][r] * accQ1[t][r] * rB[r];
            }
        }
        d0 += __shfl_xor(d0, 16); d0 += __shfl_xor(d0, 32);
        d1 += __shfl_xor(d1, 16); d1 += __shfl_xor(d1, 32);
        if (lane < 32) {
            const float inv_s = 0.08838834764831845f;  // 1/sqrt(128)
            out[e0 + lane] = (lane < 16 ? d0 : d1) * inv_s;
        }
    }
}

extern "C" void kernel_launch(void* const* d_in, const int* in_sizes, int n_in,
                              void* d_out, int out_size, void* d_ws, size_t ws_size,
                              hipStream_t stream)
{
    const float* emb = (const float*)d_in[0];
    const float* rel = (const float*)d_in[1];
    const float* tk  = (const float*)d_in[2];
    const float* tq  = (const float*)d_in[3];
    const int*   si  = (const int*)d_in[4];
    const int*   pi  = (const int*)d_in[5];
    const int*   oi  = (const int*)d_in[6];
    float* out = (float*)d_out;
    // 512 blocks x 512 threads = 2 resident blocks/CU (64 KiB LDS each),
    // 16 waves/CU; grid-stride over 31250 wave-tiles.
    sampleall_fused<<<dim3(512), dim3(512), 0, stream>>>(emb, rel, tk, tq, si, pi, oi, out);
}

// Round 3
// 488.793 us; speedup vs baseline: 2.2670x; 2.2670x over previous
//
#include <hip/hip_runtime.h>
#include <hip/hip_bf16.h>

typedef __bf16 bf16x8 __attribute__((ext_vector_type(8)));
typedef __bf16 bf16x4 __attribute__((ext_vector_type(4)));
typedef float  f32x4  __attribute__((ext_vector_type(4)));

#define EDGES_TOTAL 1000000
#define TILES (EDGES_TOTAL / 32)          // 31250 wave-tiles of 32 edges
#define EMB_ELEMS 64000000ULL             // 500000*128
#define REL_ELEMS 25600ULL                // 200*128
#define TOT_CHUNKS ((EMB_ELEMS + REL_ELEMS) / 8)
#define WS_NEEDED ((EMB_ELEMS + REL_ELEMS) * 2ULL)

__device__ __forceinline__ bf16x8 load_cvt8(const float* __restrict__ p) {
    f32x4 a = *(const f32x4*)p;
    f32x4 b = *(const f32x4*)(p + 4);
    bf16x8 r;
    r[0] = (__bf16)a[0]; r[1] = (__bf16)a[1]; r[2] = (__bf16)a[2]; r[3] = (__bf16)a[3];
    r[4] = (__bf16)b[0]; r[5] = (__bf16)b[1]; r[6] = (__bf16)b[2]; r[7] = (__bf16)b[3];
    return r;
}

// ---------- Phase 0: emb,rel f32 -> bf16 in ws (makes gather set L3-resident) ----------
__global__ __launch_bounds__(256) void cvt_bf16(
    const float* __restrict__ emb, const float* __restrict__ rel, __bf16* __restrict__ dst)
{
    const size_t stride = (size_t)gridDim.x * blockDim.x;
    for (size_t i = (size_t)blockIdx.x * blockDim.x + threadIdx.x; i < TOT_CHUNKS; i += stride) {
        size_t e = i * 8;
        const float* src = (e < EMB_ELEMS) ? emb + e : rel + (e - EMB_ELEMS);
        *(bf16x8*)(dst + e) = load_cvt8(src);
    }
}

// ---------- Phase 1: fused gather + MFMA, bf16 sources ----------
__global__ __launch_bounds__(256, 2) void sampleall_fused_b(
    const __bf16* __restrict__ embb, const __bf16* __restrict__ relb,
    const float* __restrict__ tokeys, const float* __restrict__ toqueries,
    const int* __restrict__ si, const int* __restrict__ pi, const int* __restrict__ oi,
    float* __restrict__ out)
{
    // W_k, W_q bf16 in LDS; 16B granules XOR-swizzled by (row&7) -> conflict-free ds_read_b128.
    __shared__ __align__(16) __bf16 ldsW[2][128 * 128];

    const int tid = threadIdx.x;
    #pragma unroll
    for (int it = 0; it < 16; ++it) {
        int gidx = tid + it * 256;        // 0..4095 : 2 mats x 128 rows x 16 chunks
        int m    = gidx >> 11;
        int rm   = gidx & 2047;
        int row  = rm >> 4;
        int ch   = rm & 15;
        const float* src = (m ? toqueries : tokeys) + row * 128 + ch * 8;
        bf16x8 b = load_cvt8(src);
        int byteoff = row * 256 + ((ch * 16) ^ ((row & 7) << 4));
        *(bf16x8*)((char*)(&ldsW[m][0]) + byteoff) = b;
    }
    __syncthreads();

    const int lane = tid & 63;
    const int wid  = tid >> 6;
    const int c    = lane & 15;    // edge slot within half (and W fragment row)
    const int g    = lane >> 4;    // k-group
    const int xm   = (c & 7) << 4; // LDS swizzle mask for this lane's W rows
    const char* wkbase = (const char*)(&ldsW[0][0]) + c * 256;
    const char* wqbase = (const char*)(&ldsW[1][0]) + c * 256;

    const int wtotal = (int)gridDim.x * 4;
    for (int tile = (int)blockIdx.x * 4 + wid; tile < TILES; tile += wtotal) {
        const int e0 = tile * 32;
        const int sA = si[e0 + c], sB = si[e0 + 16 + c];
        const int oA = oi[e0 + c], oB = oi[e0 + 16 + c];
        const int pA = pi[e0 + c], pB = pi[e0 + 16 + c];
        const __bf16* ps0 = embb + (size_t)sA * 128 + g * 8;
        const __bf16* ps1 = embb + (size_t)sB * 128 + g * 8;
        const __bf16* po0 = embb + (size_t)oA * 128 + g * 8;
        const __bf16* po1 = embb + (size_t)oB * 128 + g * 8;

        // Issue ALL gathers for this tile up front: 16 emb fragments (16B each)
        // + 16 rel fragments (8B each) in flight before any compute.
        bf16x8 bs0[4], bs1[4], bo0[4], bo1[4];
        #pragma unroll
        for (int j0 = 0; j0 < 4; ++j0) {
            bs0[j0] = *(const bf16x8*)(ps0 + j0 * 32);
            bs1[j0] = *(const bf16x8*)(ps1 + j0 * 32);
            bo0[j0] = *(const bf16x8*)(po0 + j0 * 32);
            bo1[j0] = *(const bf16x8*)(po1 + j0 * 32);
        }
        const __bf16* prA = relb + (size_t)pA * 128 + g * 4;
        const __bf16* prB = relb + (size_t)pB * 128 + g * 4;
        bf16x4 rA[8], rB[8];
        #pragma unroll
        for (int t = 0; t < 8; ++t) {
            rA[t] = *(const bf16x4*)(prA + t * 16);
            rB[t] = *(const bf16x4*)(prB + t * 16);
        }

        f32x4 accK0[8], accK1[8], accQ0[8], accQ1[8];
        #pragma unroll
        for (int t = 0; t < 8; ++t) {
            accK0[t] = (f32x4){0.f, 0.f, 0.f, 0.f};
            accK1[t] = (f32x4){0.f, 0.f, 0.f, 0.f};
            accQ0[t] = (f32x4){0.f, 0.f, 0.f, 0.f};
            accQ1[t] = (f32x4){0.f, 0.f, 0.f, 0.f};
        }

        #pragma unroll
        for (int j0 = 0; j0 < 4; ++j0) {
            const int offj = ((j0 * 64 + g * 16) ^ xm);   // swizzled within-row byte offset
            #pragma unroll
            for (int t = 0; t < 8; ++t) {
                bf16x8 aK = *(const bf16x8*)(wkbase + t * 4096 + offj);
                accK0[t] = __builtin_amdgcn_mfma_f32_16x16x32_bf16(aK, bs0[j0], accK0[t], 0, 0, 0);
                accK1[t] = __builtin_amdgcn_mfma_f32_16x16x32_bf16(aK, bs1[j0], accK1[t], 0, 0, 0);
                bf16x8 aQ = *(const bf16x8*)(wqbase + t * 4096 + offj);
                accQ0[t] = __builtin_amdgcn_mfma_f32_16x16x32_bf16(aQ, bo0[j0], accQ0[t], 0, 0, 0);
                accQ1[t] = __builtin_amdgcn_mfma_f32_16x16x32_bf16(aQ, bo1[j0], accQ1[t], 0, 0, 0);
            }
        }

        // Epilogue: lane (g,c) holds semb/qemb features i = t*16 + g*4 + r of its edge.
        float d0 = 0.f, d1 = 0.f;
        #pragma unroll
        for (int t = 0; t < 8; ++t) {
            #pragma unroll
            for (int r = 0; r < 4; ++r) {
                d0 += accK0[t][r] * accQ0[t][r] * (float)rA[t][r];
                d1 += accK1[t][r] * accQ1[t][r] * (float)rB[t][r];
            }
        }
        d0 += __shfl_xor(d0, 16); d0 += __shfl_xor(d0, 32);
        d1 += __shfl_xor(d1, 16); d1 += __shfl_xor(d1, 32);
        if (lane < 32) {
            const float inv_s = 0.08838834764831845f;  // 1/sqrt(128)
            out[e0 + lane] = (lane < 16 ? d0 : d1) * inv_s;
        }
    }
}

// ---------- Fallback (R1 kernel, f32 gathers) if ws is too small ----------
__global__ __launch_bounds__(256, 2) void sampleall_fused_f32(
    const float* __restrict__ emb, const float* __restrict__ rel,
    const float* __restrict__ tokeys, const float* __restrict__ toqueries,
    const int* __restrict__ si, const int* __restrict__ pi, const int* __restrict__ oi,
    float* __restrict__ out)
{
    __shared__ __align__(16) __bf16 ldsW[2][128 * 128];
    const int tid = threadIdx.x;
    #pragma unroll
    for (int it = 0; it < 16; ++it) {
        int gidx = tid + it * 256;
        int m    = gidx >> 11;
        int rm   = gidx & 2047;
        int row  = rm >> 4;
        int ch   = rm & 15;
        const float* src = (m ? toqueries : tokeys) + row * 128 + ch * 8;
        bf16x8 b = load_cvt8(src);
        int byteoff = row * 256 + ((ch * 16) ^ ((row & 7) << 4));
        *(bf16x8*)((char*)(&ldsW[m][0]) + byteoff) = b;
    }
    __syncthreads();

    const int lane = tid & 63;
    const int wid  = tid >> 6;
    const int c    = lane & 15;
    const int g    = lane >> 4;
    const int xm   = (c & 7) << 4;
    const char* wkbase = (const char*)(&ldsW[0][0]) + c * 256;
    const char* wqbase = (const char*)(&ldsW[1][0]) + c * 256;

    const int wtotal = (int)gridDim.x * 4;
    for (int tile = (int)blockIdx.x * 4 + wid; tile < TILES; tile += wtotal) {
        const int e0 = tile * 32;
        const int sA = si[e0 + c], sB = si[e0 + 16 + c];
        const int oA = oi[e0 + c], oB = oi[e0 + 16 + c];
        const int pA = pi[e0 + c], pB = pi[e0 + 16 + c];
        const float* ps0 = emb + (size_t)sA * 128 + g * 8;
        const float* ps1 = emb + (size_t)sB * 128 + g * 8;
        const float* po0 = emb + (size_t)oA * 128 + g * 8;
        const float* po1 = emb + (size_t)oB * 128 + g * 8;

        f32x4 accK0[8], accK1[8], accQ0[8], accQ1[8];
        #pragma unroll
        for (int t = 0; t < 8; ++t) {
            accK0[t] = (f32x4){0.f, 0.f, 0.f, 0.f};
            accK1[t] = (f32x4){0.f, 0.f, 0.f, 0.f};
            accQ0[t] = (f32x4){0.f, 0.f, 0.f, 0.f};
            accQ1[t] = (f32x4){0.f, 0.f, 0.f, 0.f};
        }
        #pragma unroll
        for (int j0 = 0; j0 < 4; ++j0) {
            bf16x8 bs0 = load_cvt8(ps0 + j0 * 32);
            bf16x8 bs1 = load_cvt8(ps1 + j0 * 32);
            bf16x8 bo0 = load_cvt8(po0 + j0 * 32);
            bf16x8 bo1 = load_cvt8(po1 + j0 * 32);
            const int offj = ((j0 * 64 + g * 16) ^ xm);
            #pragma unroll
            for (int t = 0; t < 8; ++t) {
                bf16x8 aK = *(const bf16x8*)(wkbase + t * 4096 + offj);
                accK0[t] = __builtin_amdgcn_mfma_f32_16x16x32_bf16(aK, bs0, accK0[t], 0, 0, 0);
                accK1[t] = __builtin_amdgcn_mfma_f32_16x16x32_bf16(aK, bs1, accK1[t], 0, 0, 0);
                bf16x8 aQ = *(const bf16x8*)(wqbase + t * 4096 + offj);
                accQ0[t] = __builtin_amdgcn_mfma_f32_16x16x32_bf16(aQ, bo0, accQ0[t], 0, 0, 0);
                accQ1[t] = __builtin_amdgcn_mfma_f32_16x16x32_bf16(aQ, bo1, accQ1[t], 0, 0, 0);
            }
        }
        float d0 = 0.f, d1 = 0.f;
        const float* relA = rel + (size_t)pA * 128 + g * 4;
        const float* relB = rel + (size_t)pB * 128 + g * 4;
        #pragma unroll
        for (int t = 0; t < 8; ++t) {
            f32x4 rA = *(const f32x4*)(relA + t * 16);
            f32x4 rB = *(const f32x4*)(relB + t * 16);
            #pragma unroll
            for (int r = 0; r < 4; ++r) {
                d0 += accK0[t][r] * accQ0[t][r] * rA[r];
                d1 += accK1[t][r] * accQ1[t][r] * rB[r];
            }
        }
        d0 += __shfl_xor(d0, 16); d0 += __shfl_xor(d0, 32);
        d1 += __shfl_xor(d1, 16); d1 += __shfl_xor(d1, 32);
        if (lane < 32) {
            const float inv_s = 0.08838834764831845f;
            out[e0 + lane] = (lane < 16 ? d0 : d1) * inv_s;
        }
    }
}

extern "C" void kernel_launch(void* const* d_in, const int* in_sizes, int n_in,
                              void* d_out, int out_size, void* d_ws, size_t ws_size,
                              hipStream_t stream)
{
    const float* emb = (const float*)d_in[0];
    const float* rel = (const float*)d_in[1];
    const float* tk  = (const float*)d_in[2];
    const float* tq  = (const float*)d_in[3];
    const int*   si  = (const int*)d_in[4];
    const int*   pi  = (const int*)d_in[5];
    const int*   oi  = (const int*)d_in[6];
    float* out = (float*)d_out;

    if (ws_size >= WS_NEEDED) {
        __bf16* embb = (__bf16*)d_ws;
        __bf16* relb = embb + EMB_ELEMS;
        cvt_bf16<<<dim3(2048), dim3(256), 0, stream>>>(emb, rel, embb);
        sampleall_fused_b<<<dim3(512), dim3(256), 0, stream>>>(embb, relb, tk, tq, si, pi, oi, out);
    } else {
        sampleall_fused_f32<<<dim3(512), dim3(256), 0, stream>>>(emb, rel, tk, tq, si, pi, oi, out);
    }
}

// Round 4
// 257.847 us; speedup vs baseline: 4.2975x; 1.8957x over previous
//
#include <hip/hip_runtime.h>
#include <hip/hip_bf16.h>

typedef __bf16 bf16x8 __attribute__((ext_vector_type(8)));
typedef float  f32x4  __attribute__((ext_vector_type(4)));

#define EDGES_TOTAL 1000000
#define TILES (EDGES_TOTAL / 32)          // 31250 tiles of 32 edges (1 tile per block-iter)
#define EMB_ELEMS 64000000ULL             // 500000*128
#define EMB_CHUNKS (EMB_ELEMS / 8)
#define WS_NEEDED (EMB_ELEMS * 2ULL)
#define GRID_BLOCKS 1024

__device__ __forceinline__ bf16x8 load_cvt8(const float* __restrict__ p) {
    f32x4 a = *(const f32x4*)p;
    f32x4 b = *(const f32x4*)(p + 4);
    bf16x8 r;
    r[0] = (__bf16)a[0]; r[1] = (__bf16)a[1]; r[2] = (__bf16)a[2]; r[3] = (__bf16)a[3];
    r[4] = (__bf16)b[0]; r[5] = (__bf16)b[1]; r[6] = (__bf16)b[2]; r[7] = (__bf16)b[3];
    return r;
}

__device__ __forceinline__ void gload_lds16(const void* g, void* l) {
    __builtin_amdgcn_global_load_lds(
        (const __attribute__((address_space(1))) void*)g,
        (__attribute__((address_space(3))) void*)l, 16, 0, 0);
}

// ---------- Phase 0: emb f32 -> bf16 in ws ----------
__global__ __launch_bounds__(256) void cvt_bf16(
    const float* __restrict__ emb, __bf16* __restrict__ dst)
{
    const size_t stride = (size_t)gridDim.x * blockDim.x;
    for (size_t i = (size_t)blockIdx.x * blockDim.x + threadIdx.x; i < EMB_CHUNKS; i += stride) {
        size_t e = i * 8;
        *(bf16x8*)(dst + e) = load_cvt8(emb + e);
    }
}

// ---------- Phase 1: block-staged gather (coalesced full rows) + MFMA ----------
// Block = 4 waves. Wave w owns output-feature slices t = 2w, 2w+1 (W frags in regs).
// All waves share one staged tile of 64 gathered emb rows in LDS (double-buffered).
__global__ __launch_bounds__(256, 3) void sampleall_staged(
    const __bf16* __restrict__ embb, const float* __restrict__ rel,
    const float* __restrict__ tokeys, const float* __restrict__ toqueries,
    const int* __restrict__ si, const int* __restrict__ pi, const int* __restrict__ oi,
    float* __restrict__ out)
{
    __shared__ __align__(16) __bf16 stage[2][64 * 128];   // 2 x 16 KiB: rows 0-31 = si, 32-63 = oi
    __shared__ float red[4][32];

    const int tid  = threadIdx.x;
    const int lane = tid & 63;
    const int wid  = tid >> 6;     // 0..3
    const int c    = lane & 15;    // edge slot / A-row / B-col
    const int g    = lane >> 4;    // k-group
    const int sub  = tid >> 4;     // 0..15: row-subgroup for staging
    const int gr   = tid & 15;     // 16B granule within row for staging

    // --- W fragments resident in registers: this wave's 2 t-slices x 4 j0 x 2 mats ---
    bf16x8 wk[2][4], wq[2][4];
    #pragma unroll
    for (int tl = 0; tl < 2; ++tl) {
        const int row = (wid * 2 + tl) * 16 + c;
        #pragma unroll
        for (int j0 = 0; j0 < 4; ++j0) {
            wk[tl][j0] = load_cvt8(tokeys    + row * 128 + j0 * 32 + g * 8);
            wq[tl][j0] = load_cvt8(toqueries + row * 128 + j0 * 32 + g * 8);
        }
    }

    // Stage one tile's 64 rows. Each global_load_lds: 16 lanes cover one full
    // 256B row -> every 128B line filled by ONE instruction (no refetch).
    // Source granule pre-swizzled (gr ^ (row&7)) so linear LDS + swizzled
    // ds_read gives conflict-free b128 reads (involution stays within the line).
    auto stage_issue = [&](int e0, int buf) {
        #pragma unroll
        for (int k = 0; k < 4; ++k) {
            const int r   = k * 16 + sub;                         // LDS row position 0..63
            const int idx = (k < 2) ? si[e0 + r] : oi[e0 + r - 32];
            const __bf16* src = embb + (size_t)idx * 128 + (gr ^ (r & 7)) * 8;
            __bf16* dst = &stage[buf][(k * 16 + (sub & ~3)) * 128];  // wave-uniform base
            gload_lds16(src, dst);
        }
    };

    auto rdfrag = [&](int buf, int p, int j0) -> bf16x8 {
        const char* base = (const char*)&stage[buf][0];
        const int off = p * 256 + ((j0 * 64 + g * 16) ^ ((p & 7) << 4));
        return *(const bf16x8*)(base + off);
    };

    int tile = (int)blockIdx.x;
    stage_issue(tile * 32, 0);
    __syncthreads();                       // drains vmcnt -> buf0 ready

    int b = 0;
    for (; tile < TILES; tile += GRID_BLOCKS) {
        const int nt = tile + GRID_BLOCKS;
        if (nt < TILES) stage_issue(nt * 32, b ^ 1);   // prefetch next tile (overlaps compute)

        const int e0 = tile * 32;
        f32x4 aK0[2], aK1[2], aQ0[2], aQ1[2];
        #pragma unroll
        for (int tl = 0; tl < 2; ++tl) {
            aK0[tl] = (f32x4){0.f, 0.f, 0.f, 0.f};
            aK1[tl] = (f32x4){0.f, 0.f, 0.f, 0.f};
            aQ0[tl] = (f32x4){0.f, 0.f, 0.f, 0.f};
            aQ1[tl] = (f32x4){0.f, 0.f, 0.f, 0.f};
        }

        #pragma unroll
        for (int j0 = 0; j0 < 4; ++j0) {
            bf16x8 bs0 = rdfrag(b, c,      j0);   // si edges 0-15
            bf16x8 bs1 = rdfrag(b, 16 + c, j0);   // si edges 16-31
            bf16x8 bo0 = rdfrag(b, 32 + c, j0);   // oi edges 0-15
            bf16x8 bo1 = rdfrag(b, 48 + c, j0);   // oi edges 16-31
            #pragma unroll
            for (int tl = 0; tl < 2; ++tl) {
                aK0[tl] = __builtin_amdgcn_mfma_f32_16x16x32_bf16(wk[tl][j0], bs0, aK0[tl], 0, 0, 0);
                aK1[tl] = __builtin_amdgcn_mfma_f32_16x16x32_bf16(wk[tl][j0], bs1, aK1[tl], 0, 0, 0);
                aQ0[tl] = __builtin_amdgcn_mfma_f32_16x16x32_bf16(wq[tl][j0], bo0, aQ0[tl], 0, 0, 0);
                aQ1[tl] = __builtin_amdgcn_mfma_f32_16x16x32_bf16(wq[tl][j0], bo1, aQ1[tl], 0, 0, 0);
            }
        }

        // Epilogue: lane (g,c), slice tl holds features f = (wid*2+tl)*16 + g*4 + r.
        const int pA = pi[e0 + c], pB = pi[e0 + 16 + c];
        float d0 = 0.f, d1 = 0.f;
        #pragma unroll
        for (int tl = 0; tl < 2; ++tl) {
            const float* ra = rel + (size_t)pA * 128 + (wid * 2 + tl) * 16 + g * 4;
            const float* rb = rel + (size_t)pB * 128 + (wid * 2 + tl) * 16 + g * 4;
            f32x4 rA = *(const f32x4*)ra;
            f32x4 rB = *(const f32x4*)rb;
            #pragma unroll
            for (int r = 0; r < 4; ++r) {
                d0 += aK0[tl][r] * aQ0[tl][r] * rA[r];
                d1 += aK1[tl][r] * aQ1[tl][r] * rB[r];
            }
        }
        d0 += __shfl_xor(d0, 16); d0 += __shfl_xor(d0, 32);   // sum over g
        d1 += __shfl_xor(d1, 16); d1 += __shfl_xor(d1, 32);
        if (lane < 16) { red[wid][c] = d0; red[wid][c + 16] = d1; }

        __syncthreads();   // red visible; vmcnt drained -> next buf staged
        if (tid < 32) {
            const float s = red[0][tid] + red[1][tid] + red[2][tid] + red[3][tid];
            out[e0 + tid] = s * 0.08838834764831845f;   // 1/sqrt(128)
        }
        __syncthreads();   // protect red (and retired buf) before next iteration
        b ^= 1;
    }
}

// ---------- Fallback (R1-style, f32 gathers, no ws) ----------
__global__ __launch_bounds__(256, 2) void sampleall_fused_f32(
    const float* __restrict__ emb, const float* __restrict__ rel,
    const float* __restrict__ tokeys, const float* __restrict__ toqueries,
    const int* __restrict__ si, const int* __restrict__ pi, const int* __restrict__ oi,
    float* __restrict__ out)
{
    __shared__ __align__(16) __bf16 ldsW[2][128 * 128];
    const int tid = threadIdx.x;
    #pragma unroll
    for (int it = 0; it < 16; ++it) {
        int gidx = tid + it * 256;
        int m    = gidx >> 11;
        int rm   = gidx & 2047;
        int row  = rm >> 4;
        int ch   = rm & 15;
        const float* src = (m ? toqueries : tokeys) + row * 128 + ch * 8;
        bf16x8 bv = load_cvt8(src);
        int byteoff = row * 256 + ((ch * 16) ^ ((row & 7) << 4));
        *(bf16x8*)((char*)(&ldsW[m][0]) + byteoff) = bv;
    }
    __syncthreads();

    const int lane = tid & 63;
    const int wid  = tid >> 6;
    const int c    = lane & 15;
    const int g    = lane >> 4;
    const int xm   = (c & 7) << 4;
    const char* wkbase = (const char*)(&ldsW[0][0]) + c * 256;
    const char* wqbase = (const char*)(&ldsW[1][0]) + c * 256;

    const int wtotal = (int)gridDim.x * 4;
    for (int tile = (int)blockIdx.x * 4 + wid; tile < TILES; tile += wtotal) {
        const int e0 = tile * 32;
        const int sA = si[e0 + c], sB = si[e0 + 16 + c];
        const int oA = oi[e0 + c], oB = oi[e0 + 16 + c];
        const int pA = pi[e0 + c], pB = pi[e0 + 16 + c];
        const float* ps0 = emb + (size_t)sA * 128 + g * 8;
        const float* ps1 = emb + (size_t)sB * 128 + g * 8;
        const float* po0 = emb + (size_t)oA * 128 + g * 8;
        const float* po1 = emb + (size_t)oB * 128 + g * 8;

        f32x4 accK0[8], accK1[8], accQ0[8], accQ1[8];
        #pragma unroll
        for (int t = 0; t < 8; ++t) {
            accK0[t] = (f32x4){0.f, 0.f, 0.f, 0.f};
            accK1[t] = (f32x4){0.f, 0.f, 0.f, 0.f};
            accQ0[t] = (f32x4){0.f, 0.f, 0.f, 0.f};
            accQ1[t] = (f32x4){0.f, 0.f, 0.f, 0.f};
        }
        #pragma unroll
        for (int j0 = 0; j0 < 4; ++j0) {
            bf16x8 bs0 = load_cvt8(ps0 + j0 * 32);
            bf16x8 bs1 = load_cvt8(ps1 + j0 * 32);
            bf16x8 bo0 = load_cvt8(po0 + j0 * 32);
            bf16x8 bo1 = load_cvt8(po1 + j0 * 32);
            const int offj = ((j0 * 64 + g * 16) ^ xm);
            #pragma unroll
            for (int t = 0; t < 8; ++t) {
                bf16x8 aK = *(const bf16x8*)(wkbase + t * 4096 + offj);
                accK0[t] = __builtin_amdgcn_mfma_f32_16x16x32_bf16(aK, bs0, accK0[t], 0, 0, 0);
                accK1[t] = __builtin_amdgcn_mfma_f32_16x16x32_bf16(aK, bs1, accK1[t], 0, 0, 0);
                bf16x8 aQ = *(const bf16x8*)(wqbase + t * 4096 + offj);
                accQ0[t] = __builtin_amdgcn_mfma_f32_16x16x32_bf16(aQ, bo0, accQ0[t], 0, 0, 0);
                accQ1[t] = __builtin_amdgcn_mfma_f32_16x16x32_bf16(aQ, bo1, accQ1[t], 0, 0, 0);
            }
        }
        float d0 = 0.f, d1 = 0.f;
        const float* relA = rel + (size_t)pA * 128 + g * 4;
        const float* relB = rel + (size_t)pB * 128 + g * 4;
        #pragma unroll
        for (int t = 0; t < 8; ++t) {
            f32x4 rA = *(const f32x4*)(relA + t * 16);
            f32x4 rB = *(const f32x4*)(relB + t * 16);
            #pragma unroll
            for (int r = 0; r < 4; ++r) {
                d0 += accK0[t][r] * accQ0[t][r] * rA[r];
                d1 += accK1[t][r] * accQ1[t][r] * rB[r];
            }
        }
        d0 += __shfl_xor(d0, 16); d0 += __shfl_xor(d0, 32);
        d1 += __shfl_xor(d1, 16); d1 += __shfl_xor(d1, 32);
        if (lane < 32) {
            const float inv_s = 0.08838834764831845f;
            out[e0 + lane] = (lane < 16 ? d0 : d1) * inv_s;
        }
    }
}

extern "C" void kernel_launch(void* const* d_in, const int* in_sizes, int n_in,
                              void* d_out, int out_size, void* d_ws, size_t ws_size,
                              hipStream_t stream)
{
    const float* emb = (const float*)d_in[0];
    const float* rel = (const float*)d_in[1];
    const float* tk  = (const float*)d_in[2];
    const float* tq  = (const float*)d_in[3];
    const int*   si  = (const int*)d_in[4];
    const int*   pi  = (const int*)d_in[5];
    const int*   oi  = (const int*)d_in[6];
    float* out = (float*)d_out;

    if (ws_size >= WS_NEEDED) {
        __bf16* embb = (__bf16*)d_ws;
        cvt_bf16<<<dim3(2048), dim3(256), 0, stream>>>(emb, embb);
        sampleall_staged<<<dim3(GRID_BLOCKS), dim3(256), 0, stream>>>(
            embb, rel, tk, tq, si, pi, oi, out);
    } else {
        sampleall_fused_f32<<<dim3(512), dim3(256), 0, stream>>>(emb, rel, tk, tq, si, pi, oi, out);
    }
}

// Round 5
// 248.653 us; speedup vs baseline: 4.4564x; 1.0370x over previous
//
#include <hip/hip_runtime.h>
#include <hip/hip_bf16.h>

typedef __bf16 bf16x8 __attribute__((ext_vector_type(8)));
typedef float  f32x4  __attribute__((ext_vector_type(4)));

#define EDGES_TOTAL 1000000
#define TILE_E 16
#define TILES (EDGES_TOTAL / TILE_E)      // 62500 tiles of 16 edges
#define EMB_ELEMS 64000000ULL             // 500000*128
#define EMB_CHUNKS (EMB_ELEMS / 8)
#define WS_NEEDED (EMB_ELEMS * 2ULL)
#define GRID_BLOCKS 1280                  // 5 blocks/CU target

__device__ __forceinline__ bf16x8 load_cvt8(const float* __restrict__ p) {
    f32x4 a = *(const f32x4*)p;
    f32x4 b = *(const f32x4*)(p + 4);
    bf16x8 r;
    r[0] = (__bf16)a[0]; r[1] = (__bf16)a[1]; r[2] = (__bf16)a[2]; r[3] = (__bf16)a[3];
    r[4] = (__bf16)b[0]; r[5] = (__bf16)b[1]; r[6] = (__bf16)b[2]; r[7] = (__bf16)b[3];
    return r;
}

__device__ __forceinline__ void gload_lds16(const void* g, void* l) {
    __builtin_amdgcn_global_load_lds(
        (const __attribute__((address_space(1))) void*)g,
        (__attribute__((address_space(3))) void*)l, 16, 0, 0);
}

// ---------- Phase 0: emb f32 -> bf16 in ws ----------
__global__ __launch_bounds__(256) void cvt_bf16(
    const float* __restrict__ emb, __bf16* __restrict__ dst)
{
    const size_t stride = (size_t)gridDim.x * blockDim.x;
    for (size_t i = (size_t)blockIdx.x * blockDim.x + threadIdx.x; i < EMB_CHUNKS; i += stride) {
        size_t e = i * 8;
        *(bf16x8*)(dst + e) = load_cvt8(emb + e);
    }
}

// ---------- Phase 1: block-staged gather + MFMA, 16-edge tiles ----------
// Block = 4 waves; wave w owns output-feature slices t = 2w, 2w+1 (W in regs).
// Per tile: 32 gathered rows (16 si + 16 oi), double-buffered 2x8KB.
// LDS ~16.9 KB/block + VGPR cap 102 -> target 5 blocks/CU (20 waves/CU).
__global__ __launch_bounds__(256, 5) void sampleall_staged(
    const __bf16* __restrict__ embb, const float* __restrict__ rel,
    const float* __restrict__ tokeys, const float* __restrict__ toqueries,
    const int* __restrict__ si, const int* __restrict__ pi, const int* __restrict__ oi,
    float* __restrict__ out)
{
    __shared__ __align__(16) __bf16 stage[2][32 * 128];   // 2 x 8 KiB: rows 0-15 = si, 16-31 = oi
    __shared__ float red[4][16];

    const int tid  = threadIdx.x;
    const int lane = tid & 63;
    const int wid  = tid >> 6;     // 0..3
    const int c    = lane & 15;    // edge slot / A-row / B-col
    const int g    = lane >> 4;    // k-group
    const int sub  = tid >> 4;     // 0..15: row-subgroup for staging
    const int gr   = tid & 15;     // 16B granule within row for staging

    // --- W fragments resident in registers: this wave's 2 t-slices x 4 j0 x 2 mats ---
    bf16x8 wk[2][4], wq[2][4];
    #pragma unroll
    for (int tl = 0; tl < 2; ++tl) {
        const int row = (wid * 2 + tl) * 16 + c;
        #pragma unroll
        for (int j0 = 0; j0 < 4; ++j0) {
            wk[tl][j0] = load_cvt8(tokeys    + row * 128 + j0 * 32 + g * 8);
            wq[tl][j0] = load_cvt8(toqueries + row * 128 + j0 * 32 + g * 8);
        }
    }

    // Stage a tile's 32 rows: 16 consecutive lanes cover one full 256B row ->
    // each 128B line requested by exactly one instruction. Source granule
    // pre-swizzled (gr ^ (row&7)); LDS dest linear (wave-uniform base).
    auto stage_issue = [&](int e0, int buf) {
        #pragma unroll
        for (int k = 0; k < 2; ++k) {
            const int r   = k * 16 + sub;                       // LDS row 0..31
            const int idx = k ? oi[e0 + sub] : si[e0 + sub];
            const __bf16* src = embb + (size_t)idx * 128 + (gr ^ (r & 7)) * 8;
            __bf16* dst = &stage[buf][(k * 16 + (sub & ~3)) * 128];  // wave-uniform
            gload_lds16(src, dst);
        }
    };

    auto rdfrag = [&](int buf, int p, int j0) -> bf16x8 {
        const char* base = (const char*)&stage[buf][0];
        const int off = p * 256 + ((j0 * 64 + g * 16) ^ ((p & 7) << 4));
        return *(const bf16x8*)(base + off);
    };

    int tile = (int)blockIdx.x;
    stage_issue(tile * TILE_E, 0);
    __syncthreads();                       // drains vmcnt -> buf0 ready

    int b = 0;
    for (; tile < TILES; tile += GRID_BLOCKS) {
        const int nt = tile + GRID_BLOCKS;
        if (nt < TILES) stage_issue(nt * TILE_E, b ^ 1);   // prefetch overlaps compute

        const int e0 = tile * TILE_E;
        f32x4 aK[2], aQ[2];
        #pragma unroll
        for (int tl = 0; tl < 2; ++tl) {
            aK[tl] = (f32x4){0.f, 0.f, 0.f, 0.f};
            aQ[tl] = (f32x4){0.f, 0.f, 0.f, 0.f};
        }

        #pragma unroll
        for (int j0 = 0; j0 < 4; ++j0) {
            bf16x8 bs = rdfrag(b, c,      j0);   // si rows
            bf16x8 bo = rdfrag(b, 16 + c, j0);   // oi rows
            #pragma unroll
            for (int tl = 0; tl < 2; ++tl) {
                aK[tl] = __builtin_amdgcn_mfma_f32_16x16x32_bf16(wk[tl][j0], bs, aK[tl], 0, 0, 0);
                aQ[tl] = __builtin_amdgcn_mfma_f32_16x16x32_bf16(wq[tl][j0], bo, aQ[tl], 0, 0, 0);
            }
        }

        // Epilogue: lane (g,c), slice tl holds features f = (wid*2+tl)*16 + g*4 + r.
        const int pA = pi[e0 + c];
        float d0 = 0.f;
        #pragma unroll
        for (int tl = 0; tl < 2; ++tl) {
            const float* ra = rel + (size_t)pA * 128 + (wid * 2 + tl) * 16 + g * 4;
            f32x4 rA = *(const f32x4*)ra;
            #pragma unroll
            for (int r = 0; r < 4; ++r)
                d0 += aK[tl][r] * aQ[tl][r] * rA[r];
        }
        d0 += __shfl_xor(d0, 16); d0 += __shfl_xor(d0, 32);   // sum over g
        if (lane < 16) red[wid][c] = d0;

        __syncthreads();   // red visible; vmcnt drained -> next buf staged
        if (tid < 16) {
            const float s = red[0][tid] + red[1][tid] + red[2][tid] + red[3][tid];
            out[e0 + tid] = s * 0.08838834764831845f;   // 1/sqrt(128)
        }
        __syncthreads();   // protect red + retired buf
        b ^= 1;
    }
}

// ---------- Fallback (R1-style, f32 gathers, no ws) ----------
__global__ __launch_bounds__(256, 2) void sampleall_fused_f32(
    const float* __restrict__ emb, const float* __restrict__ rel,
    const float* __restrict__ tokeys, const float* __restrict__ toqueries,
    const int* __restrict__ si, const int* __restrict__ pi, const int* __restrict__ oi,
    float* __restrict__ out)
{
    __shared__ __align__(16) __bf16 ldsW[2][128 * 128];
    const int tid = threadIdx.x;
    #pragma unroll
    for (int it = 0; it < 16; ++it) {
        int gidx = tid + it * 256;
        int m    = gidx >> 11;
        int rm   = gidx & 2047;
        int row  = rm >> 4;
        int ch   = rm & 15;
        const float* src = (m ? toqueries : tokeys) + row * 128 + ch * 8;
        bf16x8 bv = load_cvt8(src);
        int byteoff = row * 256 + ((ch * 16) ^ ((row & 7) << 4));
        *(bf16x8*)((char*)(&ldsW[m][0]) + byteoff) = bv;
    }
    __syncthreads();

    const int lane = tid & 63;
    const int wid  = tid >> 6;
    const int c    = lane & 15;
    const int g    = lane >> 4;
    const int xm   = (c & 7) << 4;
    const char* wkbase = (const char*)(&ldsW[0][0]) + c * 256;
    const char* wqbase = (const char*)(&ldsW[1][0]) + c * 256;

    const int wtotal = (int)gridDim.x * 4;
    for (int tile = (int)blockIdx.x * 4 + wid; tile < EDGES_TOTAL / 32; tile += wtotal) {
        const int e0 = tile * 32;
        const int sA = si[e0 + c], sB = si[e0 + 16 + c];
        const int oA = oi[e0 + c], oB = oi[e0 + 16 + c];
        const int pA = pi[e0 + c], pB = pi[e0 + 16 + c];
        const float* ps0 = emb + (size_t)sA * 128 + g * 8;
        const float* ps1 = emb + (size_t)sB * 128 + g * 8;
        const float* po0 = emb + (size_t)oA * 128 + g * 8;
        const float* po1 = emb + (size_t)oB * 128 + g * 8;

        f32x4 accK0[8], accK1[8], accQ0[8], accQ1[8];
        #pragma unroll
        for (int t = 0; t < 8; ++t) {
            accK0[t] = (f32x4){0.f, 0.f, 0.f, 0.f};
            accK1[t] = (f32x4){0.f, 0.f, 0.f, 0.f};
            accQ0[t] = (f32x4){0.f, 0.f, 0.f, 0.f};
            accQ1[t] = (f32x4){0.f, 0.f, 0.f, 0.f};
        }
        #pragma unroll
        for (int j0 = 0; j0 < 4; ++j0) {
            bf16x8 bs0 = load_cvt8(ps0 + j0 * 32);
            bf16x8 bs1 = load_cvt8(ps1 + j0 * 32);
            bf16x8 bo0 = load_cvt8(po0 + j0 * 32);
            bf16x8 bo1 = load_cvt8(po1 + j0 * 32);
            const int offj = ((j0 * 64 + g * 16) ^ xm);
            #pragma unroll
            for (int t = 0; t < 8; ++t) {
                bf16x8 aK = *(const bf16x8*)(wkbase + t * 4096 + offj);
                accK0[t] = __builtin_amdgcn_mfma_f32_16x16x32_bf16(aK, bs0, accK0[t], 0, 0, 0);
                accK1[t] = __builtin_amdgcn_mfma_f32_16x16x32_bf16(aK, bs1, accK1[t], 0, 0, 0);
                bf16x8 aQ = *(const bf16x8*)(wqbase + t * 4096 + offj);
                accQ0[t] = __builtin_amdgcn_mfma_f32_16x16x32_bf16(aQ, bo0, accQ0[t], 0, 0, 0);
                accQ1[t] = __builtin_amdgcn_mfma_f32_16x16x32_bf16(aQ, bo1, accQ1[t], 0, 0, 0);
            }
        }
        float d0 = 0.f, d1 = 0.f;
        const float* relA = rel + (size_t)pA * 128 + g * 4;
        const float* relB = rel + (size_t)pB * 128 + g * 4;
        #pragma unroll
        for (int t = 0; t < 8; ++t) {
            f32x4 rA = *(const f32x4*)(relA + t * 16);
            f32x4 rB = *(const f32x4*)(relB + t * 16);
            #pragma unroll
            for (int r = 0; r < 4; ++r) {
                d0 += accK0[t][r] * accQ0[t][r] * rA[r];
                d1 += accK1[t][r] * accQ1[t][r] * rB[r];
            }
        }
        d0 += __shfl_xor(d0, 16); d0 += __shfl_xor(d0, 32);
        d1 += __shfl_xor(d1, 16); d1 += __shfl_xor(d1, 32);
        if (lane < 32) {
            const float inv_s = 0.08838834764831845f;
            out[e0 + lane] = (lane < 16 ? d0 : d1) * inv_s;
        }
    }
}

extern "C" void kernel_launch(void* const* d_in, const int* in_sizes, int n_in,
                              void* d_out, int out_size, void* d_ws, size_t ws_size,
                              hipStream_t stream)
{
    const float* emb = (const float*)d_in[0];
    const float* rel = (const float*)d_in[1];
    const float* tk  = (const float*)d_in[2];
    const float* tq  = (const float*)d_in[3];
    const int*   si  = (const int*)d_in[4];
    const int*   pi  = (const int*)d_in[5];
    const int*   oi  = (const int*)d_in[6];
    float* out = (float*)d_out;

    if (ws_size >= WS_NEEDED) {
        __bf16* embb = (__bf16*)d_ws;
        cvt_bf16<<<dim3(2048), dim3(256), 0, stream>>>(emb, embb);
        sampleall_staged<<<dim3(GRID_BLOCKS), dim3(256), 0, stream>>>(
            embb, rel, tk, tq, si, pi, oi, out);
    } else {
        sampleall_fused_f32<<<dim3(512), dim3(256), 0, stream>>>(emb, rel, tk, tq, si, pi, oi, out);
    }
}